// Round 1
// baseline (639.936 us; speedup 1.0000x reference)
//
#include <hip/hip_runtime.h>
#include <math.h>

typedef unsigned short u16;
typedef __attribute__((ext_vector_type(4))) unsigned short u16x4;
typedef __attribute__((ext_vector_type(8))) short short8;
typedef __attribute__((ext_vector_type(4))) float f32x4;

// ---------- helpers ----------
__device__ __forceinline__ void gl_lds16(const void* g, void* s) {
  // async global->LDS, 16B per lane. LDS dest = wave-uniform base + lane*16.
  __builtin_amdgcn_global_load_lds((const __attribute__((address_space(1))) void*)g,
                                   (__attribute__((address_space(3))) void*)s, 16, 0, 0);
}

__device__ __forceinline__ u16 f2bf(float f) {
  union { float f; unsigned u; } a; a.f = f;
  unsigned r = a.u + 0x7fff + ((a.u >> 16) & 1);   // RNE to bf16
  return (u16)(r >> 16);
}

// ---------- LayerNorm + cast to bf16 ----------
__global__ __launch_bounds__(256) void ln_kernel(const float* __restrict__ src,
                                                 const float* __restrict__ g,
                                                 const float* __restrict__ b,
                                                 u16* __restrict__ out) {
  int row = blockIdx.x;
  int t = threadIdx.x;
  const float4* s4 = (const float4*)(src + (size_t)row * 1024);
  float4 x = s4[t];
  float s1 = x.x + x.y + x.z + x.w;
  float s2 = x.x * x.x + x.y * x.y + x.z * x.z + x.w * x.w;
  for (int m = 32; m; m >>= 1) { s1 += __shfl_xor(s1, m); s2 += __shfl_xor(s2, m); }
  __shared__ float red[8];
  int w = t >> 6, lane = t & 63;
  if (lane == 0) { red[w] = s1; red[4 + w] = s2; }
  __syncthreads();
  float tot  = red[0] + red[1] + red[2] + red[3];
  float tot2 = red[4] + red[5] + red[6] + red[7];
  float mean = tot * (1.0f / 1024.0f);
  float var  = tot2 * (1.0f / 1024.0f) - mean * mean;
  float rs = rsqrtf(var + 1e-5f);
  float4 gg = ((const float4*)g)[t];
  float4 bb = ((const float4*)b)[t];
  u16x4 o;
  o[0] = f2bf((x.x - mean) * rs * gg.x + bb.x);
  o[1] = f2bf((x.y - mean) * rs * gg.y + bb.y);
  o[2] = f2bf((x.z - mean) * rs * gg.z + bb.z);
  o[3] = f2bf((x.w - mean) * rs * gg.w + bb.w);
  ((u16x4*)(out + (size_t)row * 1024))[t] = o;
}

// ---------- transpose + cast weights: in (K x N) f32 -> out (N x K) bf16 ----------
__global__ __launch_bounds__(256) void tcast_kernel(const float* __restrict__ in,
                                                    u16* __restrict__ out, int K, int N) {
  __shared__ float tt[64][65];
  int t = threadIdx.x;
  int n0 = blockIdx.x * 64, k0 = blockIdx.y * 64;
  #pragma unroll
  for (int s = 0; s < 4; ++s) {
    int idx = s * 256 + t;
    int r = idx >> 4, c4 = idx & 15;
    float4 v = *(const float4*)(in + (size_t)(k0 + r) * N + n0 + c4 * 4);
    tt[r][c4 * 4 + 0] = v.x; tt[r][c4 * 4 + 1] = v.y;
    tt[r][c4 * 4 + 2] = v.z; tt[r][c4 * 4 + 3] = v.w;
  }
  __syncthreads();
  #pragma unroll
  for (int s = 0; s < 4; ++s) {
    int idx = s * 256 + t;
    int nr = idx >> 4, kc = idx & 15;
    u16x4 o;
    o[0] = f2bf(tt[kc * 4 + 0][nr]);
    o[1] = f2bf(tt[kc * 4 + 1][nr]);
    o[2] = f2bf(tt[kc * 4 + 2][nr]);
    o[3] = f2bf(tt[kc * 4 + 3][nr]);
    *(u16x4*)(out + (size_t)(n0 + nr) * K + k0 + kc * 4) = o;
  }
}

// ---------- GEMM: C = A(MxK) * Bt(NxK)^T, 128x128 tile, BK=32, 4 waves ----------
// EPI 0: scatter to Q/K/Vt (bf16)   EPI 1: y = resid + acc + bias -> f32 + bf16
// EPI 2: gelu(acc + bias) -> bf16   EPI 3: out = resid + acc + bias -> f32
template <int EPI>
__global__ __launch_bounds__(256, 2) void gemm_kernel(
    const u16* __restrict__ A, const u16* __restrict__ Bt,
    int M, int N, int K,
    const float* __restrict__ bias, const float* __restrict__ resid,
    float* __restrict__ outf, u16* __restrict__ outh,
    u16* __restrict__ qo, u16* __restrict__ ko, u16* __restrict__ vo) {
  __shared__ u16 lA[128 * 32];
  __shared__ u16 lB[128 * 32];
  int t = threadIdx.x, w = t >> 6, lane = t & 63;
  int bm = blockIdx.x, bn = blockIdx.y;
  int wm = (w >> 1) * 64, wn = (w & 1) * 64;
  int am = lane & 15, ag = lane >> 4;
  f32x4 acc[4][4];
  #pragma unroll
  for (int i = 0; i < 4; ++i)
    #pragma unroll
    for (int j = 0; j < 4; ++j)
      #pragma unroll
      for (int r = 0; r < 4; ++r) acc[i][j][r] = 0.f;

  const size_t rowA0 = (size_t)bm * 128, colB0 = (size_t)bn * 128;

  for (int k0 = 0; k0 < K; k0 += 32) {
    #pragma unroll
    for (int s = 0; s < 2; ++s) {
      int c = s * 256 + w * 64 + lane;
      int row = c >> 2, cc = c & 3;
      int scc = cc ^ ((row >> 1) & 3);               // XOR-swizzled source -> swizzled LDS
      gl_lds16(A  + (rowA0 + row) * K + k0 + scc * 8, (char*)lA + (size_t)(s * 256 + w * 64) * 16);
      gl_lds16(Bt + (colB0 + row) * K + k0 + scc * 8, (char*)lB + (size_t)(s * 256 + w * 64) * 16);
    }
    __syncthreads();
    short8 af[4], bfr[4];
    #pragma unroll
    for (int i = 0; i < 4; ++i) {
      int row = wm + i * 16 + am;
      int ch = ag ^ ((row >> 1) & 3);
      af[i] = *(const short8*)(lA + row * 32 + ch * 8);
    }
    #pragma unroll
    for (int j = 0; j < 4; ++j) {
      int row = wn + j * 16 + am;
      int ch = ag ^ ((row >> 1) & 3);
      bfr[j] = *(const short8*)(lB + row * 32 + ch * 8);
    }
    #pragma unroll
    for (int i = 0; i < 4; ++i)
      #pragma unroll
      for (int j = 0; j < 4; ++j)
        acc[i][j] = __builtin_amdgcn_mfma_f32_16x16x32_bf16(af[i], bfr[j], acc[i][j], 0, 0, 0);
    __syncthreads();
  }

  #pragma unroll
  for (int i = 0; i < 4; ++i) {
    #pragma unroll
    for (int j = 0; j < 4; ++j) {
      #pragma unroll
      for (int r = 0; r < 4; ++r) {
        int grow = (int)rowA0 + wm + i * 16 + ag * 4 + r;
        int gcol = (int)colB0 + wn + j * 16 + am;
        float v = acc[i][j][r];
        if (EPI == 0) {
          int which = gcol >> 10, hh = (gcol >> 6) & 15, d = gcol & 63;
          int n = grow >> 2, bb = grow & 3;
          size_t hoff = (size_t)(bb * 16 + hh);
          if (which == 0)      qo[(hoff * 2048 + n) * 64 + d] = f2bf(v);
          else if (which == 1) ko[(hoff * 2048 + n) * 64 + d] = f2bf(v);
          else                 vo[hoff * 64 * 2048 + (size_t)d * 2048 + n] = f2bf(v);
        } else if (EPI == 1) {
          size_t idx = (size_t)grow * 1024 + gcol;
          float y = resid[idx] + v + bias[gcol];
          outf[idx] = y;
          outh[idx] = f2bf(y);
        } else if (EPI == 2) {
          float x = v + bias[gcol];
          float ge = 0.5f * x * (1.0f + erff(x * 0.70710678118654752f));
          outh[(size_t)grow * 4096 + gcol] = f2bf(ge);
        } else {
          size_t idx = (size_t)grow * 1024 + gcol;
          outf[idx] = resid[idx] + v + bias[gcol];
        }
      }
    }
  }
}

// ---------- flash attention: Q,K (B,H,N,hd) bf16, Vt (B,H,hd,N) bf16 ----------
// Output scattered into "mixed" layout reproducing o.transpose(2,1,0,3).reshape(N,B,C).
__global__ __launch_bounds__(256, 2) void attn_kernel(const u16* __restrict__ Q,
                                                      const u16* __restrict__ Kt,
                                                      const u16* __restrict__ Vt,
                                                      u16* __restrict__ Omix) {
  __shared__ u16 Qs[64 * 64], Ks[64 * 64], Vs[64 * 64];
  __shared__ u16 Ps[4][16 * 72];
  int t = threadIdx.x, w = t >> 6, lane = t & 63;
  int qb = blockIdx.x, bh = blockIdx.y;
  int bb = bh >> 4, hh = bh & 15;
  const u16* qbase = Q  + ((size_t)bh * 2048 + (size_t)qb * 64) * 64;
  const u16* kbase = Kt + (size_t)bh * 2048 * 64;
  const u16* vbase = Vt + (size_t)bh * 64 * 2048;
  int am = lane & 15, ag = lane >> 4;

  #pragma unroll
  for (int s = 0; s < 2; ++s) {
    int c = (w * 2 + s) * 64 + lane;
    int row = c >> 3, cc = c & 7;
    int scc = cc ^ (row & 7);
    gl_lds16(qbase + row * 64 + scc * 8, (char*)Qs + (size_t)(w * 2 + s) * 64 * 16);
  }
  __syncthreads();
  short8 qf[2];
  #pragma unroll
  for (int hf = 0; hf < 2; ++hf) {
    int row = w * 16 + am;
    int ch = (hf * 4 + ag) ^ (row & 7);
    qf[hf] = *(const short8*)(Qs + row * 64 + ch * 8);
  }

  float m[4], l[4];
  f32x4 o[4];
  #pragma unroll
  for (int r = 0; r < 4; ++r) { m[r] = -3.0e38f; l[r] = 0.f; }
  #pragma unroll
  for (int j = 0; j < 4; ++j)
    #pragma unroll
    for (int r = 0; r < 4; ++r) o[j][r] = 0.f;

  for (int kt = 0; kt < 32; ++kt) {
    int n0 = kt * 64;
    #pragma unroll
    for (int s = 0; s < 2; ++s) {
      int c = (w * 2 + s) * 64 + lane;
      int row = c >> 3, cc = c & 7;
      int scc = cc ^ (row & 7);
      gl_lds16(kbase + (size_t)(n0 + row) * 64 + scc * 8, (char*)Ks + (size_t)(w * 2 + s) * 64 * 16);
      gl_lds16(vbase + (size_t)row * 2048 + n0 + scc * 8, (char*)Vs + (size_t)(w * 2 + s) * 64 * 16);
    }
    __syncthreads();

    f32x4 sacc[4];
    #pragma unroll
    for (int jf = 0; jf < 4; ++jf)
      #pragma unroll
      for (int r = 0; r < 4; ++r) sacc[jf][r] = 0.f;
    #pragma unroll
    for (int jf = 0; jf < 4; ++jf) {
      #pragma unroll
      for (int hf = 0; hf < 2; ++hf) {
        int row = jf * 16 + am;
        int ch = (hf * 4 + ag) ^ (row & 7);
        short8 kf = *(const short8*)(Ks + row * 64 + ch * 8);
        sacc[jf] = __builtin_amdgcn_mfma_f32_16x16x32_bf16(qf[hf], kf, sacc[jf], 0, 0, 0);
      }
    }

    float pv[4][4], alpha[4];
    #pragma unroll
    for (int r = 0; r < 4; ++r) {
      float mx = fmaxf(fmaxf(sacc[0][r], sacc[1][r]), fmaxf(sacc[2][r], sacc[3][r])) * 0.125f;
      for (int msk = 1; msk < 16; msk <<= 1) mx = fmaxf(mx, __shfl_xor(mx, msk));
      float mnew = fmaxf(m[r], mx);
      alpha[r] = __expf(m[r] - mnew);
      float rs = 0.f;
      #pragma unroll
      for (int jf = 0; jf < 4; ++jf) {
        float p = __expf(sacc[jf][r] * 0.125f - mnew);
        pv[jf][r] = p;
        rs += p;
      }
      for (int msk = 1; msk < 16; msk <<= 1) rs += __shfl_xor(rs, msk);
      l[r] = l[r] * alpha[r] + rs;
      m[r] = mnew;
    }
    #pragma unroll
    for (int jf = 0; jf < 4; ++jf)
      #pragma unroll
      for (int r = 0; r < 4; ++r) o[jf][r] *= alpha[r];

    u16* pw = Ps[w];
    #pragma unroll
    for (int jf = 0; jf < 4; ++jf)
      #pragma unroll
      for (int r = 0; r < 4; ++r)
        pw[(ag * 4 + r) * 72 + jf * 16 + am] = f2bf(pv[jf][r]);

    short8 pf[2];
    #pragma unroll
    for (int kc = 0; kc < 2; ++kc)
      pf[kc] = *(const short8*)(pw + am * 72 + kc * 32 + ag * 8);

    #pragma unroll
    for (int jf = 0; jf < 4; ++jf) {
      #pragma unroll
      for (int kc = 0; kc < 2; ++kc) {
        int row = jf * 16 + am;
        int ch = (kc * 4 + ag) ^ (row & 7);
        short8 vf = *(const short8*)(Vs + row * 64 + ch * 8);
        o[jf] = __builtin_amdgcn_mfma_f32_16x16x32_bf16(pf[kc], vf, o[jf], 0, 0, 0);
      }
    }
    __syncthreads();
  }

  #pragma unroll
  for (int jf = 0; jf < 4; ++jf) {
    #pragma unroll
    for (int r = 0; r < 4; ++r) {
      int qrow = qb * 64 + w * 16 + ag * 4 + r;   // = n
      int d = jf * 16 + am;
      float val = o[jf][r] / l[r];
      Omix[((size_t)qrow * 4 + (hh >> 2)) * 1024 + (hh & 3) * 256 + bb * 64 + d] = f2bf(val);
    }
  }
}

// ---------- launcher ----------
extern "C" void kernel_launch(void* const* d_in, const int* in_sizes, int n_in,
                              void* d_out, int out_size, void* d_ws, size_t ws_size,
                              hipStream_t stream) {
  const float* src    = (const float*)d_in[0];
  const float* ln_g   = (const float*)d_in[1];
  const float* ln_b   = (const float*)d_in[2];
  const float* w_qkv  = (const float*)d_in[3];
  const float* w_proj = (const float*)d_in[4];
  const float* b_proj = (const float*)d_in[5];
  const float* w1     = (const float*)d_in[6];
  const float* b1     = (const float*)d_in[7];
  const float* w2     = (const float*)d_in[8];
  const float* b2     = (const float*)d_in[9];

  char* ws = (char*)d_ws;
  // byte offsets
  u16* wqkvT  = (u16*)(ws + 0);            // 3072x1024 bf16  (6 MB)
  u16* wprojT = (u16*)(ws + 6291456);      // 1024x1024 bf16  (2 MB)
  u16* w1T    = (u16*)(ws + 8388608);      // 4096x1024 bf16  (8 MB)
  u16* w2T    = (u16*)(ws + 16777216);     // 1024x4096 bf16  (8 MB)
  u16* xln    = (u16*)(ws + 25165824);     // 8192x1024 bf16  (16 MB) — reused as Omix
  u16* Omix   = xln;
  u16* Qp     = (u16*)(ws + 41943040);     // (B,H,N,hd) bf16 (16 MB)
  u16* Kp     = (u16*)(ws + 58720256);     // (B,H,N,hd) bf16 (16 MB)
  u16* Vp     = (u16*)(ws + 75497472);     // (B,H,hd,N) bf16 (16 MB)
  u16* hbuf   = (u16*)(ws + 41943040);     // 8192x4096 bf16  (64 MB) — overlays Q/K/V
  u16* ybf    = (u16*)(ws + 109051904);    // 8192x1024 bf16  (16 MB)
  float* yf   = (float*)d_out;             // 8192x1024 f32 residual (in-place with out)

  dim3 blk(256);
  tcast_kernel<<<dim3(48, 16), blk, 0, stream>>>(w_qkv, wqkvT, 1024, 3072);
  tcast_kernel<<<dim3(16, 16), blk, 0, stream>>>(w_proj, wprojT, 1024, 1024);
  tcast_kernel<<<dim3(64, 16), blk, 0, stream>>>(w1, w1T, 1024, 4096);
  tcast_kernel<<<dim3(16, 64), blk, 0, stream>>>(w2, w2T, 4096, 1024);
  ln_kernel<<<8192, blk, 0, stream>>>(src, ln_g, ln_b, xln);

  gemm_kernel<0><<<dim3(64, 24), blk, 0, stream>>>(xln, wqkvT, 8192, 3072, 1024,
      nullptr, nullptr, nullptr, nullptr, Qp, Kp, Vp);

  attn_kernel<<<dim3(32, 64), blk, 0, stream>>>(Qp, Kp, Vp, Omix);

  gemm_kernel<1><<<dim3(64, 8), blk, 0, stream>>>(Omix, wprojT, 8192, 1024, 1024,
      b_proj, src, yf, ybf, nullptr, nullptr, nullptr);

  gemm_kernel<2><<<dim3(64, 32), blk, 0, stream>>>(ybf, w1T, 8192, 4096, 1024,
      b1, nullptr, nullptr, hbuf, nullptr, nullptr, nullptr);

  gemm_kernel<3><<<dim3(64, 8), blk, 0, stream>>>(hbuf, w2T, 8192, 1024, 4096,
      b2, yf, (float*)d_out, nullptr, nullptr, nullptr, nullptr);
}

// Round 3
// 593.882 us; speedup vs baseline: 1.0775x; 1.0775x over previous
//
#include <hip/hip_runtime.h>
#include <hip/hip_bf16.h>
#include <math.h>

typedef unsigned short u16;
typedef __attribute__((ext_vector_type(4))) unsigned short u16x4;
typedef __attribute__((ext_vector_type(8))) short short8;
typedef __attribute__((ext_vector_type(4))) float f32x4;
typedef __attribute__((ext_vector_type(16))) float f32x16;

// ---------- helpers ----------
__device__ __forceinline__ void gl_lds16(const void* g, void* s) {
  __builtin_amdgcn_global_load_lds((const __attribute__((address_space(1))) void*)g,
                                   (__attribute__((address_space(3))) void*)s, 16, 0, 0);
}

__device__ __forceinline__ u16 f2bf(float f) {
  union { float f; unsigned u; } a; a.f = f;
  unsigned r = a.u + 0x7fff + ((a.u >> 16) & 1);
  return (u16)(r >> 16);
}

__device__ __forceinline__ unsigned pk2(float a, float b) {
  union { __hip_bfloat162 h; unsigned u; } cv;
  cv.h = __float22bfloat162_rn(make_float2(a, b));
  return cv.u;
}

__device__ __forceinline__ short8 mk8(unsigned a, unsigned b, unsigned c, unsigned d) {
  union { unsigned u[4]; short8 v; } cv;
  cv.u[0] = a; cv.u[1] = b; cv.u[2] = c; cv.u[3] = d; return cv.v;
}

__device__ __forceinline__ short8 scale8(short8 v, float s) {
  short8 r;
  #pragma unroll
  for (int i = 0; i < 8; ++i) {
    union { float f; unsigned u; } a; a.u = ((unsigned)(u16)v[i]) << 16;
    r[i] = (short)f2bf(a.f * s);
  }
  return r;
}

__device__ __forceinline__ f32x16 z16() {
  f32x16 z;
  #pragma unroll
  for (int i = 0; i < 16; ++i) z[i] = 0.f;
  return z;
}

// ---------- LayerNorm + cast to bf16 ----------
__global__ __launch_bounds__(256) void ln_kernel(const float* __restrict__ src,
                                                 const float* __restrict__ g,
                                                 const float* __restrict__ b,
                                                 u16* __restrict__ out) {
  int row = blockIdx.x;
  int t = threadIdx.x;
  const float4* s4 = (const float4*)(src + (size_t)row * 1024);
  float4 x = s4[t];
  float s1 = x.x + x.y + x.z + x.w;
  float s2 = x.x * x.x + x.y * x.y + x.z * x.z + x.w * x.w;
  for (int m = 32; m; m >>= 1) { s1 += __shfl_xor(s1, m); s2 += __shfl_xor(s2, m); }
  __shared__ float red[8];
  int w = t >> 6, lane = t & 63;
  if (lane == 0) { red[w] = s1; red[4 + w] = s2; }
  __syncthreads();
  float tot  = red[0] + red[1] + red[2] + red[3];
  float tot2 = red[4] + red[5] + red[6] + red[7];
  float mean = tot * (1.0f / 1024.0f);
  float var  = tot2 * (1.0f / 1024.0f) - mean * mean;
  float rs = rsqrtf(var + 1e-5f);
  float4 gg = ((const float4*)g)[t];
  float4 bb = ((const float4*)b)[t];
  u16x4 o;
  o[0] = f2bf((x.x - mean) * rs * gg.x + bb.x);
  o[1] = f2bf((x.y - mean) * rs * gg.y + bb.y);
  o[2] = f2bf((x.z - mean) * rs * gg.z + bb.z);
  o[3] = f2bf((x.w - mean) * rs * gg.w + bb.w);
  ((u16x4*)(out + (size_t)row * 1024))[t] = o;
}

// ---------- transpose + cast weights: in (K x N) f32 -> out (N x K) bf16 ----------
__global__ __launch_bounds__(256) void tcast_kernel(const float* __restrict__ in,
                                                    u16* __restrict__ out, int K, int N) {
  __shared__ float tt[64][65];
  int t = threadIdx.x;
  int n0 = blockIdx.x * 64, k0 = blockIdx.y * 64;
  #pragma unroll
  for (int s = 0; s < 4; ++s) {
    int idx = s * 256 + t;
    int r = idx >> 4, c4 = idx & 15;
    float4 v = *(const float4*)(in + (size_t)(k0 + r) * N + n0 + c4 * 4);
    tt[r][c4 * 4 + 0] = v.x; tt[r][c4 * 4 + 1] = v.y;
    tt[r][c4 * 4 + 2] = v.z; tt[r][c4 * 4 + 3] = v.w;
  }
  __syncthreads();
  #pragma unroll
  for (int s = 0; s < 4; ++s) {
    int idx = s * 256 + t;
    int nr = idx >> 4, kc = idx & 15;
    u16x4 o;
    o[0] = f2bf(tt[kc * 4 + 0][nr]);
    o[1] = f2bf(tt[kc * 4 + 1][nr]);
    o[2] = f2bf(tt[kc * 4 + 2][nr]);
    o[3] = f2bf(tt[kc * 4 + 3][nr]);
    *(u16x4*)(out + (size_t)(n0 + nr) * K + k0 + kc * 4) = o;
  }
}

// ---------- V transpose + sigma-permute: qkv V-part -> Vt (b,h,d, pos) ----------
// position p holds kv = (p & ~15) | sigma(p&15), sigma: swap middle 4-blocks.
__global__ __launch_bounds__(256) void vtrans_kernel(const u16* __restrict__ qkv,
                                                     u16* __restrict__ vt) {
  __shared__ u16 tile[64][66];
  int t = threadIdx.x;
  int nt = blockIdx.x, bh = blockIdx.y;
  int bb = bh >> 4, hh = bh & 15;
  int n0 = nt * 64;
  #pragma unroll
  for (int s = 0; s < 2; ++s) {
    int idx = s * 256 + t;
    int i = idx >> 3, c = idx & 7;
    union { short8 v; unsigned u[4]; } cv;
    cv.v = *(const short8*)(qkv + (size_t)((n0 + i) * 4 + bb) * 3072 + 2048 + hh * 64 + c * 8);
    unsigned* dst = (unsigned*)&tile[i][c * 8];
    dst[0] = cv.u[0]; dst[1] = cv.u[1]; dst[2] = cv.u[2]; dst[3] = cv.u[3];
  }
  __syncthreads();
  #pragma unroll
  for (int s = 0; s < 2; ++s) {
    int idx = s * 256 + t;
    int d = idx >> 3, ch = idx & 7;
    union { u16 e[8]; short8 v; } ov;
    #pragma unroll
    for (int j = 0; j < 8; ++j) {
      int P = ch * 8 + j;
      int q = P & 15, blk = q >> 2;
      int bp = ((blk & 1) << 1) | (blk >> 1);
      int src = (P & ~15) | (bp << 2) | (q & 3);
      ov.e[j] = tile[src][d];
    }
    *(short8*)(vt + ((size_t)(bh * 64 + d)) * 2048 + n0 + ch * 8) = ov.v;
  }
}

// ---------- GEMM: C = A(MxK) * Bt(NxK)^T, 128x128 tile, BK=32, 4 waves ----------
// EPI 0: plain bf16 store      EPI 1: y = resid + acc + bias -> f32 + bf16
// EPI 2: gelu(acc+bias)->bf16  EPI 3: out = resid + acc + bias -> f32
template <int EPI>
__global__ __launch_bounds__(256, 2) void gemm_kernel(
    const u16* __restrict__ A, const u16* __restrict__ Bt,
    int M, int N, int K,
    const float* __restrict__ bias, const float* __restrict__ resid,
    float* __restrict__ outf, u16* __restrict__ outh, int ldo) {
  __shared__ u16 lA[128 * 32];
  __shared__ u16 lB[128 * 32];
  int t = threadIdx.x, w = t >> 6, lane = t & 63;
  int bm = blockIdx.x, bn = blockIdx.y;
  int wm = (w >> 1) * 64, wn = (w & 1) * 64;
  int am = lane & 15, ag = lane >> 4;
  f32x4 acc[4][4];
  #pragma unroll
  for (int i = 0; i < 4; ++i)
    #pragma unroll
    for (int j = 0; j < 4; ++j)
      #pragma unroll
      for (int r = 0; r < 4; ++r) acc[i][j][r] = 0.f;

  const size_t rowA0 = (size_t)bm * 128, colB0 = (size_t)bn * 128;

  for (int k0 = 0; k0 < K; k0 += 32) {
    #pragma unroll
    for (int s = 0; s < 2; ++s) {
      int c = s * 256 + w * 64 + lane;
      int row = c >> 2, cc = c & 3;
      int scc = cc ^ ((row >> 1) & 3);
      gl_lds16(A  + (rowA0 + row) * K + k0 + scc * 8, (char*)lA + (size_t)(s * 256 + w * 64) * 16);
      gl_lds16(Bt + (colB0 + row) * K + k0 + scc * 8, (char*)lB + (size_t)(s * 256 + w * 64) * 16);
    }
    __syncthreads();
    short8 af[4], bfr[4];
    #pragma unroll
    for (int i = 0; i < 4; ++i) {
      int row = wm + i * 16 + am;
      int ch = ag ^ ((row >> 1) & 3);
      af[i] = *(const short8*)(lA + row * 32 + ch * 8);
    }
    #pragma unroll
    for (int j = 0; j < 4; ++j) {
      int row = wn + j * 16 + am;
      int ch = ag ^ ((row >> 1) & 3);
      bfr[j] = *(const short8*)(lB + row * 32 + ch * 8);
    }
    #pragma unroll
    for (int i = 0; i < 4; ++i)
      #pragma unroll
      for (int j = 0; j < 4; ++j)
        acc[i][j] = __builtin_amdgcn_mfma_f32_16x16x32_bf16(af[i], bfr[j], acc[i][j], 0, 0, 0);
    __syncthreads();
  }

  #pragma unroll
  for (int i = 0; i < 4; ++i) {
    #pragma unroll
    for (int j = 0; j < 4; ++j) {
      #pragma unroll
      for (int r = 0; r < 4; ++r) {
        int grow = (int)rowA0 + wm + i * 16 + ag * 4 + r;
        int gcol = (int)colB0 + wn + j * 16 + am;
        float v = acc[i][j][r];
        if (EPI == 0) {
          outh[(size_t)grow * ldo + gcol] = f2bf(v);
        } else if (EPI == 1) {
          size_t idx = (size_t)grow * 1024 + gcol;
          float y = resid[idx] + v + bias[gcol];
          outf[idx] = y;
          outh[idx] = f2bf(y);
        } else if (EPI == 2) {
          float x = v + bias[gcol];
          float ge = 0.5f * x * (1.0f + erff(x * 0.70710678118654752f));
          outh[(size_t)grow * ldo + gcol] = f2bf(ge);
        } else {
          size_t idx = (size_t)grow * 1024 + gcol;
          outf[idx] = resid[idx] + v + bias[gcol];
        }
      }
    }
  }
}

// ---------- flash attention, swapped 32x32 structure ----------
// qkv: (8192 x 3072) bf16 rows = n*4+b; cols [0,1024)=Q, [1024,2048)=K, [2048,3072)=V.
// Vt: (b*16+h, d=64, pos=2048) bf16, sigma-permuted positions.
// Omix reproduces o.transpose(2,1,0,3).reshape(N,B,C).
#define SOFTMAX(S0, S1, MM, LL, OA, OB, WDS) { \
  float smax = S0[0]; \
  _Pragma("unroll") for (int i = 1; i < 16; ++i) smax = fmaxf(smax, S0[i]); \
  _Pragma("unroll") for (int i = 0; i < 16; ++i) smax = fmaxf(smax, S1[i]); \
  smax = fmaxf(smax, __shfl_xor(smax, 32)); \
  if (!__all(smax <= MM + 11.5416f)) { \
    float mn = fmaxf(MM, smax); float al = exp2f(MM - mn); \
    LL *= al; \
    _Pragma("unroll") for (int i = 0; i < 16; ++i) { OA[i] *= al; OB[i] *= al; } \
    MM = mn; \
  } \
  float rsum = 0.f; \
  _Pragma("unroll") for (int j = 0; j < 8; ++j) { \
    float ea = exp2f(S0[2*j] - MM), eb = exp2f(S0[2*j+1] - MM); \
    rsum += ea + eb; WDS[j] = pk2(ea, eb); } \
  _Pragma("unroll") for (int j = 0; j < 8; ++j) { \
    float ea = exp2f(S1[2*j] - MM), eb = exp2f(S1[2*j+1] - MM); \
    rsum += ea + eb; WDS[8+j] = pk2(ea, eb); } \
  rsum += __shfl_xor(rsum, 32); \
  LL += rsum; }

__global__ __launch_bounds__(256) void attn_kernel(const u16* __restrict__ qkv,
                                                   const u16* __restrict__ Vt,
                                                   u16* __restrict__ Omix) {
  __shared__ u16 Ks[2][64 * 64];
  __shared__ u16 Vs[2][64 * 64];
  const int t = threadIdx.x, w = t >> 6, lane = t & 63, l31 = lane & 31, hi = lane >> 5;
  const int qb = blockIdx.x, bh = blockIdx.y, bb = bh >> 4, hh = bh & 15;
  const float SC = 0.125f * 1.44269504f;   // scale * log2(e)

  // Q fragments (scaled, in exp2 domain)
  short8 qf[2][4];
  #pragma unroll
  for (int qt = 0; qt < 2; ++qt)
    #pragma unroll
    for (int kc = 0; kc < 4; ++kc) {
      int qn = qb * 256 + w * 64 + qt * 32 + l31;
      const u16* p = qkv + (size_t)(qn * 4 + bb) * 3072 + hh * 64 + kc * 16 + hi * 8;
      qf[qt][kc] = scale8(*(const short8*)p, SC);
    }

  float m0 = -1e30f, l0 = 0.f, m1 = -1e30f, l1 = 0.f;
  f32x16 o00 = z16(), o01 = z16(), o10 = z16(), o11 = z16();

#define STAGE(BUF, KT) { \
  int n0_ = (KT) * 64; \
  _Pragma("unroll") \
  for (int s2 = 0; s2 < 2; ++s2) { \
    int idx = s2 * 256 + t; \
    int row = idx >> 3, c = idx & 7, sc = c ^ (row & 7); \
    gl_lds16(qkv + (size_t)((n0_ + row) * 4 + bb) * 3072 + 1024 + hh * 64 + sc * 8, \
             (char*)&Ks[BUF][0] + (s2 * 256 + w * 64) * 16); \
    gl_lds16(Vt + ((size_t)(bh * 64 + row)) * 2048 + n0_ + sc * 8, \
             (char*)&Vs[BUF][0] + (s2 * 256 + w * 64) * 16); \
  } }

  int cur = 0;
  STAGE(0, 0);
  __syncthreads();

  for (int kt = 0; kt < 32; ++kt) {
    if (kt < 31) STAGE(cur ^ 1, kt + 1);
    const char* Kb = (const char*)&Ks[cur][0];
    const char* Vb = (const char*)&Vs[cur][0];

    // K fragments (shared by both q-subtiles)
    short8 kf0[4], kf1[4];
    #pragma unroll
    for (int kc = 0; kc < 4; ++kc) {
      int r0 = l31, r1 = 32 + l31;
      kf0[kc] = *(const short8*)(Kb + r0 * 128 + (((kc * 2 + hi) ^ (r0 & 7)) * 16));
      kf1[kc] = *(const short8*)(Kb + r1 * 128 + (((kc * 2 + hi) ^ (r1 & 7)) * 16));
    }

    // qt0: S^T = K * Q
    f32x16 sA = z16(), sB = z16();
    #pragma unroll
    for (int kc = 0; kc < 4; ++kc) {
      sA = __builtin_amdgcn_mfma_f32_32x32x16_bf16(kf0[kc], qf[0][kc], sA, 0, 0, 0);
      sB = __builtin_amdgcn_mfma_f32_32x32x16_bf16(kf1[kc], qf[0][kc], sB, 0, 0, 0);
    }
    unsigned wd0[16];
    SOFTMAX(sA, sB, m0, l0, o00, o01, wd0);

    // qt1
    f32x16 sC = z16(), sD = z16();
    #pragma unroll
    for (int kc = 0; kc < 4; ++kc) {
      sC = __builtin_amdgcn_mfma_f32_32x32x16_bf16(kf0[kc], qf[1][kc], sC, 0, 0, 0);
      sD = __builtin_amdgcn_mfma_f32_32x32x16_bf16(kf1[kc], qf[1][kc], sD, 0, 0, 0);
    }
    unsigned wd1[16];
    SOFTMAX(sC, sD, m1, l1, o10, o11, wd1);

    // V^T fragments (shared by both q-subtiles)
    short8 vf0[4], vf1[4];
    #pragma unroll
    for (int st = 0; st < 4; ++st) {
      int r0 = l31, r1 = 32 + l31;
      vf0[st] = *(const short8*)(Vb + r0 * 128 + (((st * 2 + hi) ^ (r0 & 7)) * 16));
      vf1[st] = *(const short8*)(Vb + r1 * 128 + (((st * 2 + hi) ^ (r1 & 7)) * 16));
    }

    // PV: O^T += V^T * P^T  (B-frag = wds[4s..4s+3] directly, sigma-permuted)
    #pragma unroll
    for (int st = 0; st < 4; ++st) {
      short8 bA = mk8(wd0[4 * st], wd0[4 * st + 1], wd0[4 * st + 2], wd0[4 * st + 3]);
      o00 = __builtin_amdgcn_mfma_f32_32x32x16_bf16(vf0[st], bA, o00, 0, 0, 0);
      o01 = __builtin_amdgcn_mfma_f32_32x32x16_bf16(vf1[st], bA, o01, 0, 0, 0);
      short8 bB = mk8(wd1[4 * st], wd1[4 * st + 1], wd1[4 * st + 2], wd1[4 * st + 3]);
      o10 = __builtin_amdgcn_mfma_f32_32x32x16_bf16(vf0[st], bB, o10, 0, 0, 0);
      o11 = __builtin_amdgcn_mfma_f32_32x32x16_bf16(vf1[st], bB, o11, 0, 0, 0);
    }

    __syncthreads();
    cur ^= 1;
  }

  float r0 = 1.f / l0, r1 = 1.f / l1;
  #pragma unroll
  for (int qt = 0; qt < 2; ++qt) {
    float rl = qt ? r1 : r0;
    int qn = qb * 256 + w * 64 + qt * 32 + l31;
    size_t base = ((size_t)(qn * 4 + (hh >> 2))) * 1024 + (hh & 3) * 256 + bb * 64;
    #pragma unroll
    for (int dt = 0; dt < 2; ++dt) {
      #pragma unroll
      for (int reg = 0; reg < 16; ++reg) {
        int d = dt * 32 + (reg & 3) + 8 * (reg >> 2) + 4 * hi;
        float val = (qt ? (dt ? o11[reg] : o10[reg]) : (dt ? o01[reg] : o00[reg])) * rl;
        Omix[base + d] = f2bf(val);
      }
    }
  }
}

// ---------- launcher ----------
extern "C" void kernel_launch(void* const* d_in, const int* in_sizes, int n_in,
                              void* d_out, int out_size, void* d_ws, size_t ws_size,
                              hipStream_t stream) {
  const float* src    = (const float*)d_in[0];
  const float* ln_g   = (const float*)d_in[1];
  const float* ln_b   = (const float*)d_in[2];
  const float* w_qkv  = (const float*)d_in[3];
  const float* w_proj = (const float*)d_in[4];
  const float* b_proj = (const float*)d_in[5];
  const float* b1     = (const float*)d_in[7];
  const float* w1     = (const float*)d_in[6];
  const float* w2     = (const float*)d_in[8];
  const float* b2     = (const float*)d_in[9];

  char* ws = (char*)d_ws;
  u16* wqkvT  = (u16*)(ws + 0);            // 3072x1024 bf16  (6 MB)
  u16* wprojT = (u16*)(ws + 6291456);      // 1024x1024 bf16  (2 MB)
  u16* w1T    = (u16*)(ws + 8388608);      // 4096x1024 bf16  (8 MB)
  u16* w2T    = (u16*)(ws + 16777216);     // 1024x4096 bf16  (8 MB)
  u16* xln    = (u16*)(ws + 25165824);     // 8192x1024 bf16  (16 MB) — reused as Omix
  u16* Omix   = xln;
  u16* qkv    = (u16*)(ws + 41943040);     // 8192x3072 bf16  (48 MB)
  u16* Vtb    = (u16*)(ws + 92274688);     // (b,h,64,2048) bf16 (16 MB)
  u16* hbuf   = (u16*)(ws + 41943040);     // 8192x4096 bf16  (64 MB) — overlays qkv+Vt
  u16* ybf    = (u16*)(ws + 109051904);    // 8192x1024 bf16  (16 MB)
  float* yf   = (float*)d_out;             // 8192x1024 f32 residual (in-place with out)

  dim3 blk(256);
  tcast_kernel<<<dim3(48, 16), blk, 0, stream>>>(w_qkv, wqkvT, 1024, 3072);
  tcast_kernel<<<dim3(16, 16), blk, 0, stream>>>(w_proj, wprojT, 1024, 1024);
  tcast_kernel<<<dim3(64, 16), blk, 0, stream>>>(w1, w1T, 1024, 4096);
  tcast_kernel<<<dim3(16, 64), blk, 0, stream>>>(w2, w2T, 4096, 1024);
  ln_kernel<<<8192, blk, 0, stream>>>(src, ln_g, ln_b, xln);

  gemm_kernel<0><<<dim3(64, 24), blk, 0, stream>>>(xln, wqkvT, 8192, 3072, 1024,
      nullptr, nullptr, nullptr, qkv, 3072);

  vtrans_kernel<<<dim3(32, 64), blk, 0, stream>>>(qkv, Vtb);

  attn_kernel<<<dim3(8, 64), blk, 0, stream>>>(qkv, Vtb, Omix);

  gemm_kernel<1><<<dim3(64, 8), blk, 0, stream>>>(Omix, wprojT, 8192, 1024, 1024,
      b_proj, src, yf, ybf, 1024);

  gemm_kernel<2><<<dim3(64, 32), blk, 0, stream>>>(ybf, w1T, 8192, 4096, 1024,
      b1, nullptr, nullptr, hbuf, 4096);

  gemm_kernel<3><<<dim3(64, 8), blk, 0, stream>>>(hbuf, w2T, 8192, 1024, 4096,
      b2, yf, (float*)d_out, nullptr, 1024);
}